// Round 7
// baseline (490.013 us; speedup 1.0000x reference)
//
#include <hip/hip_runtime.h>

#define HW    (128*128)
#define DHW   (128*128*128)
#define NTOT  (4*DHW)
#define NBLK  (16*128*4)   // reduce_all block count = 8192

__device__ __forceinline__ float sigf(float x){ return 1.0f/(1.0f+__expf(-x)); }
__device__ __forceinline__ float4 ld4(const float* p){ return *(const float4*)p; }

// ws float layout: acc[0]=occ, acc[1]=surf, acc[2]=over, acc[3]=counter(uint bits),
//                  acc[4..7]=per-batch trap box deltas

// ---------------------------------------------------------------------------
// Resin-trap box sim. Deviation from the background fixed point
// m_bg = a_lo*(1-v) is confined to Manhattan distance <= 10 from seed (5,5,5),
// i.e. cells [0,15]^3. Simulate exactly (iter 1 analytic + 9 iterations).
// NO per-thread arrays (R4/R6 spilled to scratch at VGPR 76 < 80 floats):
// mask lives in two padded LDS boxes [17][17][20]; index 16 in each + axis
// holds the constant background a_lo*(1-v) (pre-filled in BOTH buffers);
// - faces are out-of-grid -> 0 via tiny conditionals. nv in LDS too.
// block (4,16,16)=1024 thr (16 waves); thread owns x-quad. grid = 4 batches.
// Also zeroes the global accumulators (runs before reduce_all in stream).
// ---------------------------------------------------------------------------
__global__ __launch_bounds__(1024) void trap_box_k(
    const float* __restrict__ v, float* __restrict__ acc)
{
    __shared__ float mbuf[2][17][17][20];
    __shared__ float nvL[16][16][20];
    __shared__ float red[16];

    const int b = blockIdx.x;
    const size_t gb = (size_t)b * DHW;
    const int tx = threadIdx.x, ty = threadIdx.y, tz = threadIdx.z;
    const int tid = (tz*16 + ty)*4 + tx;
    const int x4 = tx*4;
    const float a_lo = sigf(-10.0f), a_hi = sigf(10.0f);

    if (b == 0 && tid < 4) acc[tid] = 0.0f;   // occ,surf,over sums + counter=0

    // interior init: nv and analytic iteration-1 mask
    float4 vq = ld4(v + gb + ((size_t)tz*128 + ty)*128 + x4);
    {
        float nv0=1.f-vq.x, nv1=1.f-vq.y, nv2=1.f-vq.z, nv3=1.f-vq.w;
        nvL[tz][ty][x4+0]=nv0; nvL[tz][ty][x4+1]=nv1;
        nvL[tz][ty][x4+2]=nv2; nvL[tz][ty][x4+3]=nv3;
        int dzy = abs(tz-5) + abs(ty-5);
        int d0 = dzy + abs(x4+0-5), d1 = dzy + abs(x4+1-5);
        int d2 = dzy + abs(x4+2-5), d3 = dzy + abs(x4+3-5);
        mbuf[0][tz][ty][x4+0] = ((d0==0)?1.f:((d0==1)?a_hi:a_lo)) * nv0;
        mbuf[0][tz][ty][x4+1] = ((d1==0)?1.f:((d1==1)?a_hi:a_lo)) * nv1;
        mbuf[0][tz][ty][x4+2] = ((d2==0)?1.f:((d2==1)?a_hi:a_lo)) * nv2;
        mbuf[0][tz][ty][x4+3] = ((d3==0)?1.f:((d3==1)?a_hi:a_lo)) * nv3;
    }
    // background +faces into BOTH buffers (constant across iterations)
    for (int i = tid; i < 3*256; i += 1024) {
        int f = i >> 8, c = i & 255;
        int a = c >> 4, e = c & 15;
        int zz, yy, xx;
        if (f == 0)      { zz = 16; yy = a;  xx = e;  }
        else if (f == 1) { zz = a;  yy = 16; xx = e;  }
        else             { zz = a;  yy = e;  xx = 16; }
        float bgv = a_lo * (1.f - v[gb + ((size_t)zz*128 + yy)*128 + xx]);
        mbuf[0][zz][yy][xx] = bgv;
        mbuf[1][zz][yy][xx] = bgv;
    }
    __syncthreads();

    float m0=0.f, m1=0.f, m2=0.f, m3=0.f;
    int cur = 0;
    for (int it = 0; it < 9; ++it) {
        const float* C  = &mbuf[cur][tz][ty][0];
        float c0 = C[x4+0], c1 = C[x4+1], c2 = C[x4+2], c3 = C[x4+3];
        float xl = (tx > 0) ? C[x4-1] : 0.f;    // x=-1 out of grid
        float xr = C[x4+4];                      // x4+4 <= 16 always valid (16 = bg)
        const float* YM = &mbuf[cur][tz][ty-1][0];   // guarded below
        const float* YP = &mbuf[cur][tz][ty+1][0];   // ty+1 <= 16 valid (bg row)
        const float* ZM = &mbuf[cur][tz-1][ty][0];
        const float* ZP = &mbuf[cur][tz+1][ty][0];
        float ym0=0,ym1=0,ym2=0,ym3=0, zm0=0,zm1=0,zm2=0,zm3=0;
        if (ty > 0) { ym0=YM[x4+0]; ym1=YM[x4+1]; ym2=YM[x4+2]; ym3=YM[x4+3]; }
        if (tz > 0) { zm0=ZM[x4+0]; zm1=ZM[x4+1]; zm2=ZM[x4+2]; zm3=ZM[x4+3]; }
        float yp0=YP[x4+0], yp1=YP[x4+1], yp2=YP[x4+2], yp3=YP[x4+3];
        float zp0=ZP[x4+0], zp1=ZP[x4+1], zp2=ZP[x4+2], zp3=ZP[x4+3];
        float nv0=nvL[tz][ty][x4+0], nv1=nvL[tz][ty][x4+1];
        float nv2=nvL[tz][ty][x4+2], nv3=nvL[tz][ty][x4+3];

        float s0 = xl + c1 + ym0 + yp0 + zm0 + zp0;
        float s1 = c0 + c2 + ym1 + yp1 + zm1 + zp1;
        float s2 = c1 + c3 + ym2 + yp2 + zm2 + zp2;
        float s3 = c2 + xr + ym3 + yp3 + zm3 + zp3;
        m0 = fmaxf(c0, sigf(20.f*s0 - 10.f)) * nv0;
        m1 = fmaxf(c1, sigf(20.f*s1 - 10.f)) * nv1;
        m2 = fmaxf(c2, sigf(20.f*s2 - 10.f)) * nv2;
        m3 = fmaxf(c3, sigf(20.f*s3 - 10.f)) * nv3;
        float* W = &mbuf[cur^1][tz][ty][0];
        W[x4+0]=m0; W[x4+1]=m1; W[x4+2]=m2; W[x4+3]=m3;
        __syncthreads();
        cur ^= 1;
    }

    // delta vs background fixed point
    float d = (m0 - a_lo*(1.f-vq.x)) + (m1 - a_lo*(1.f-vq.y))
            + (m2 - a_lo*(1.f-vq.z)) + (m3 - a_lo*(1.f-vq.w));
    #pragma unroll
    for (int o = 32; o; o >>= 1) d += __shfl_down(d, o, 64);
    int lane = tid & 63, wid = tid >> 6;
    if (lane == 0) red[wid] = d;
    __syncthreads();
    if (tid == 0) {
        float t = 0.f;
        #pragma unroll
        for (int w = 0; w < 16; ++w) t += red[w];
        acc[4 + b] = t;
    }
}

// ---------------------------------------------------------------------------
// reduce_all: occupancy / surface / overhang in one pass over v.
// block (32,8) tile: y rows [y0..y0+7] of slice z. The below-plane rows
// y0-1..y0+8 (zero-padded OOB, plus zeroed x=-1/x=128 edge words) are staged
// in LDS once per block -> all 9-point reads are LDS, no shuffles/branches.
// Block partials go to device-scope float atomics; the last block (counter)
// combines with the trap deltas and writes both outputs.
// ---------------------------------------------------------------------------
__global__ __launch_bounds__(256) void reduce_all_k(
    const float* __restrict__ v, float* __restrict__ acc,
    float* __restrict__ out)
{
    __shared__ float rows[10][132];   // stride 132: row r+1 shifted 4 banks
    __shared__ float sm[3][4];

    const int tx = threadIdx.x, ty = threadIdx.y;
    const int tid = ty*32 + tx;
    const int y0 = blockIdx.x*8;
    const int y  = y0 + ty;
    const int z  = blockIdx.y;
    const int b  = blockIdx.z;
    const int x4 = tx*4;
    const size_t idx = (size_t)b*DHW + ((size_t)z*128 + y)*128 + x4;

    if (z >= 1) {
        const float* bp = v + (size_t)b*DHW + (size_t)(z-1)*HW;
        const float4 zero = make_float4(0,0,0,0);
        for (int i = tid; i < 320; i += 256) {
            int r = i >> 5, q = (i & 31)*4;
            int gy = y0 - 1 + r;
            float4 qv = ((unsigned)gy <= 127u) ? ld4(bp + (size_t)gy*128 + q) : zero;
            *(float4*)&rows[r][q] = qv;
        }
        if (tid < 20) rows[tid>>1][130 + (tid&1)] = 0.f;
    }
    __syncthreads();

    float4 val = ld4(v + idx);
    float occ = val.x + val.y + val.z + val.w;

    float wz = (z==0 || z==127) ? 2.f : 3.f;
    float wy = (y==0 || y==127) ? 2.f : 3.f;
    float wx0 = (x4==0)   ? 2.f : 3.f;
    float wx3 = (x4==124) ? 2.f : 3.f;
    float surf = wz*wy*(wx0*val.x + 3.f*val.y + 3.f*val.z + wx3*val.w);

    float over = 0.f;
    if (z >= 1) {
        float sx=0, sy=0, szz=0, sw=0;
        #pragma unroll
        for (int dy = 0; dy < 3; ++dy) {
            const float* R = rows[ty + dy];
            float4 q = *(const float4*)&R[x4];
            float ql = R[(tx==0)  ? 130 : x4-1];
            float qr = R[(tx==31) ? 131 : x4+4];
            sx  += ql  + q.x + q.y;
            sy  += q.x + q.y + q.z;
            szz += q.y + q.z + q.w;
            sw  += q.z + q.w + qr;
        }
        const float inv9 = 1.f/9.f;
        over = val.x*(1.f - sx*inv9) + val.y*(1.f - sy*inv9)
             + val.z*(1.f - szz*inv9) + val.w*(1.f - sw*inv9);
    }

    #pragma unroll
    for (int o = 32; o; o >>= 1) {
        occ  += __shfl_down(occ,  o, 64);
        surf += __shfl_down(surf, o, 64);
        over += __shfl_down(over, o, 64);
    }
    int lane = tid & 63, wid = tid >> 6;
    if (lane == 0) { sm[0][wid]=occ; sm[1][wid]=surf; sm[2][wid]=over; }
    __syncthreads();
    if (tid == 0) {
        atomicAdd(acc+0, sm[0][0]+sm[0][1]+sm[0][2]+sm[0][3]);
        atomicAdd(acc+1, sm[1][0]+sm[1][1]+sm[1][2]+sm[1][3]);
        atomicAdd(acc+2, sm[2][0]+sm[2][1]+sm[2][2]+sm[2][3]);
        __threadfence();
        if (atomicAdd((unsigned int*)(acc+3), 1u) == NBLK-1) {
            __threadfence();
            double so = (double)atomicAdd(acc+0, 0.0f);   // coherent reads
            double ss = (double)atomicAdd(acc+1, 0.0f);
            double sv = (double)atomicAdd(acc+2, 0.0f);
            double dS = (double)acc[4] + acc[5] + acc[6] + acc[7]; // prior dispatch
            double a_lo = 1.0 / (1.0 + exp(10.0));
            double N = (double)NTOT;
            double trap_sum = a_lo * (N - so) + dS;
            double occupancy = so / N;
            double occ_pen = 10.0 * (occupancy - 0.5) * (occupancy - 0.5);
            out[0] = (float)(sv / N);
            out[1] = (float)(ss / 27.0 / N - 100.0 * trap_sum / N - occ_pen);
        }
    }
}

extern "C" void kernel_launch(void* const* d_in, const int* in_sizes, int n_in,
                              void* d_out, int out_size, void* d_ws, size_t ws_size,
                              hipStream_t stream)
{
    const float* v = (const float*)d_in[0];
    float* out = (float*)d_out;
    float* acc = (float*)d_ws;   // 8 floats

    // trap_box zeroes acc[0..3] and writes acc[4..7]; stream order makes it
    // a graph dependency of reduce_all, whose last block finalizes into out.
    trap_box_k<<<4, dim3(4,16,16), 0, stream>>>(v, acc);
    reduce_all_k<<<dim3(16,128,4), dim3(32,8,1), 0, stream>>>(v, acc, out);
}

// Round 8
// 96.490 us; speedup vs baseline: 5.0784x; 5.0784x over previous
//
#include <hip/hip_runtime.h>

#define HW    (128*128)
#define DHW   (128*128*128)
#define NTOT  (4*DHW)
#define NBLK  (16*128*4)   // reduce_all block count = 8192

__device__ __forceinline__ float sigf(float x){ return 1.0f/(1.0f+__expf(-x)); }
__device__ __forceinline__ float4 ld4(const float* p){ return *(const float4*)p; }

// ws float layout: p_occ[NBLK], p_surf[NBLK], p_over[NBLK], p_trap[4]

// ---------------------------------------------------------------------------
// Resin-trap box sim. Deviation from the background fixed point
// m_bg = a_lo*(1-v) is confined to Manhattan distance <= 10 from seed (5,5,5),
// i.e. cells [0,15]^3. Simulate exactly (iter 1 analytic + 9 iterations).
// No per-thread arrays (register-array versions spilled): mask in two padded
// LDS boxes [17][17][20] whose +faces hold the constant background; -faces
// are out-of-grid (0) via conditionals. 1024 threads, thread owns an x-quad.
// grid = 4 batches. Writes per-batch delta sum(m10 - a_lo*(1-v)) to p_trap.
// ---------------------------------------------------------------------------
__global__ __launch_bounds__(1024) void trap_box_k(
    const float* __restrict__ v, float* __restrict__ p_trap)
{
    __shared__ float mbuf[2][17][17][20];
    __shared__ float nvL[16][16][20];
    __shared__ float red[16];

    const int b = blockIdx.x;
    const size_t gb = (size_t)b * DHW;
    const int tx = threadIdx.x, ty = threadIdx.y, tz = threadIdx.z;
    const int tid = (tz*16 + ty)*4 + tx;
    const int x4 = tx*4;
    const float a_lo = sigf(-10.0f), a_hi = sigf(10.0f);

    // interior init: nv and analytic iteration-1 mask
    float4 vq = ld4(v + gb + ((size_t)tz*128 + ty)*128 + x4);
    {
        float nv0=1.f-vq.x, nv1=1.f-vq.y, nv2=1.f-vq.z, nv3=1.f-vq.w;
        nvL[tz][ty][x4+0]=nv0; nvL[tz][ty][x4+1]=nv1;
        nvL[tz][ty][x4+2]=nv2; nvL[tz][ty][x4+3]=nv3;
        int dzy = abs(tz-5) + abs(ty-5);
        int d0 = dzy + abs(x4+0-5), d1 = dzy + abs(x4+1-5);
        int d2 = dzy + abs(x4+2-5), d3 = dzy + abs(x4+3-5);
        mbuf[0][tz][ty][x4+0] = ((d0==0)?1.f:((d0==1)?a_hi:a_lo)) * nv0;
        mbuf[0][tz][ty][x4+1] = ((d1==0)?1.f:((d1==1)?a_hi:a_lo)) * nv1;
        mbuf[0][tz][ty][x4+2] = ((d2==0)?1.f:((d2==1)?a_hi:a_lo)) * nv2;
        mbuf[0][tz][ty][x4+3] = ((d3==0)?1.f:((d3==1)?a_hi:a_lo)) * nv3;
    }
    // background +faces into BOTH buffers (constant across iterations)
    for (int i = tid; i < 3*256; i += 1024) {
        int f = i >> 8, c = i & 255;
        int a = c >> 4, e = c & 15;
        int zz, yy, xx;
        if (f == 0)      { zz = 16; yy = a;  xx = e;  }
        else if (f == 1) { zz = a;  yy = 16; xx = e;  }
        else             { zz = a;  yy = e;  xx = 16; }
        float bgv = a_lo * (1.f - v[gb + ((size_t)zz*128 + yy)*128 + xx]);
        mbuf[0][zz][yy][xx] = bgv;
        mbuf[1][zz][yy][xx] = bgv;
    }
    __syncthreads();

    float m0=0.f, m1=0.f, m2=0.f, m3=0.f;
    int cur = 0;
    for (int it = 0; it < 9; ++it) {
        const float* C  = &mbuf[cur][tz][ty][0];
        float c0 = C[x4+0], c1 = C[x4+1], c2 = C[x4+2], c3 = C[x4+3];
        float xl = (tx > 0) ? C[x4-1] : 0.f;    // x=-1 out of grid
        float xr = C[x4+4];                      // x4+4 <= 16 valid (16 = bg)
        const float* YM = &mbuf[cur][tz][ty-1][0];
        const float* YP = &mbuf[cur][tz][ty+1][0];   // ty+1 <= 16 valid (bg row)
        const float* ZM = &mbuf[cur][tz-1][ty][0];
        const float* ZP = &mbuf[cur][tz+1][ty][0];
        float ym0=0,ym1=0,ym2=0,ym3=0, zm0=0,zm1=0,zm2=0,zm3=0;
        if (ty > 0) { ym0=YM[x4+0]; ym1=YM[x4+1]; ym2=YM[x4+2]; ym3=YM[x4+3]; }
        if (tz > 0) { zm0=ZM[x4+0]; zm1=ZM[x4+1]; zm2=ZM[x4+2]; zm3=ZM[x4+3]; }
        float yp0=YP[x4+0], yp1=YP[x4+1], yp2=YP[x4+2], yp3=YP[x4+3];
        float zp0=ZP[x4+0], zp1=ZP[x4+1], zp2=ZP[x4+2], zp3=ZP[x4+3];
        float nv0=nvL[tz][ty][x4+0], nv1=nvL[tz][ty][x4+1];
        float nv2=nvL[tz][ty][x4+2], nv3=nvL[tz][ty][x4+3];

        float s0 = xl + c1 + ym0 + yp0 + zm0 + zp0;
        float s1 = c0 + c2 + ym1 + yp1 + zm1 + zp1;
        float s2 = c1 + c3 + ym2 + yp2 + zm2 + zp2;
        float s3 = c2 + xr + ym3 + yp3 + zm3 + zp3;
        m0 = fmaxf(c0, sigf(20.f*s0 - 10.f)) * nv0;
        m1 = fmaxf(c1, sigf(20.f*s1 - 10.f)) * nv1;
        m2 = fmaxf(c2, sigf(20.f*s2 - 10.f)) * nv2;
        m3 = fmaxf(c3, sigf(20.f*s3 - 10.f)) * nv3;
        float* W = &mbuf[cur^1][tz][ty][0];
        W[x4+0]=m0; W[x4+1]=m1; W[x4+2]=m2; W[x4+3]=m3;
        __syncthreads();
        cur ^= 1;
    }

    // delta vs background fixed point
    float d = (m0 - a_lo*(1.f-vq.x)) + (m1 - a_lo*(1.f-vq.y))
            + (m2 - a_lo*(1.f-vq.z)) + (m3 - a_lo*(1.f-vq.w));
    #pragma unroll
    for (int o = 32; o; o >>= 1) d += __shfl_down(d, o, 64);
    int lane = tid & 63, wid = tid >> 6;
    if (lane == 0) red[wid] = d;
    __syncthreads();
    if (tid == 0) {
        float t = 0.f;
        #pragma unroll
        for (int w = 0; w < 16; ++w) t += red[w];
        p_trap[b] = t;
    }
}

// ---------------------------------------------------------------------------
// reduce_all: occupancy / surface / overhang in one pass over v.
// block (32,8) tile: y rows [y0..y0+7] of slice z. Below-plane rows
// y0-1..y0+8 (zero-padded OOB + zeroed edge words) staged in LDS via b128;
// all 9-point reads are LDS. Per-block partials to ws — NO global atomics
// (R7: 8192 same-address atomics serialized -> 418 us).
// ---------------------------------------------------------------------------
__global__ __launch_bounds__(256) void reduce_all_k(
    const float* __restrict__ v, float* __restrict__ p_occ,
    float* __restrict__ p_surf, float* __restrict__ p_over)
{
    __shared__ float rows[10][132];
    __shared__ float sm[3][4];

    const int tx = threadIdx.x, ty = threadIdx.y;
    const int tid = ty*32 + tx;
    const int y0 = blockIdx.x*8;
    const int y  = y0 + ty;
    const int z  = blockIdx.y;
    const int b  = blockIdx.z;
    const int x4 = tx*4;
    const size_t idx = (size_t)b*DHW + ((size_t)z*128 + y)*128 + x4;

    if (z >= 1) {
        const float* bp = v + (size_t)b*DHW + (size_t)(z-1)*HW;
        const float4 zero = make_float4(0,0,0,0);
        for (int i = tid; i < 320; i += 256) {
            int r = i >> 5, q = (i & 31)*4;
            int gy = y0 - 1 + r;
            float4 qv = ((unsigned)gy <= 127u) ? ld4(bp + (size_t)gy*128 + q) : zero;
            *(float4*)&rows[r][q] = qv;
        }
        if (tid < 20) rows[tid>>1][130 + (tid&1)] = 0.f;
    }
    __syncthreads();

    float4 val = ld4(v + idx);
    float occ = val.x + val.y + val.z + val.w;

    float wz = (z==0 || z==127) ? 2.f : 3.f;
    float wy = (y==0 || y==127) ? 2.f : 3.f;
    float wx0 = (x4==0)   ? 2.f : 3.f;
    float wx3 = (x4==124) ? 2.f : 3.f;
    float surf = wz*wy*(wx0*val.x + 3.f*val.y + 3.f*val.z + wx3*val.w);

    float over = 0.f;
    if (z >= 1) {
        float sx=0, sy=0, szz=0, sw=0;
        #pragma unroll
        for (int dy = 0; dy < 3; ++dy) {
            const float* R = rows[ty + dy];
            float4 q = *(const float4*)&R[x4];
            float ql = R[(tx==0)  ? 130 : x4-1];
            float qr = R[(tx==31) ? 131 : x4+4];
            sx  += ql  + q.x + q.y;
            sy  += q.x + q.y + q.z;
            szz += q.y + q.z + q.w;
            sw  += q.z + q.w + qr;
        }
        const float inv9 = 1.f/9.f;
        over = val.x*(1.f - sx*inv9) + val.y*(1.f - sy*inv9)
             + val.z*(1.f - szz*inv9) + val.w*(1.f - sw*inv9);
    }

    #pragma unroll
    for (int o = 32; o; o >>= 1) {
        occ  += __shfl_down(occ,  o, 64);
        surf += __shfl_down(surf, o, 64);
        over += __shfl_down(over, o, 64);
    }
    int lane = tid & 63, wid = tid >> 6;
    if (lane == 0) { sm[0][wid]=occ; sm[1][wid]=surf; sm[2][wid]=over; }
    __syncthreads();
    if (tid == 0) {
        int blin = (b*gridDim.y + blockIdx.y)*gridDim.x + blockIdx.x;
        p_occ [blin] = sm[0][0]+sm[0][1]+sm[0][2]+sm[0][3];
        p_surf[blin] = sm[1][0]+sm[1][1]+sm[1][2]+sm[1][3];
        p_over[blin] = sm[2][0]+sm[2][1]+sm[2][2]+sm[2][3];
    }
}

// ---------------------------------------------------------------------------
// finalize: sum partials (f64), combine with trap deltas.
// trap_sum = a_lo*(N - sum(v)) + sum(box deltas)
// ---------------------------------------------------------------------------
__global__ __launch_bounds__(1024) void finalize_k(
    const float* __restrict__ p_occ, const float* __restrict__ p_surf,
    const float* __restrict__ p_over, const float* __restrict__ p_trap,
    float* __restrict__ out)
{
    double occ=0, surf=0, over=0;
    for (int i = threadIdx.x; i < NBLK; i += 1024) {
        occ += p_occ[i]; surf += p_surf[i]; over += p_over[i];
    }
    __shared__ double sm[3][16];
    #pragma unroll
    for (int o = 32; o; o >>= 1) {
        occ  += __shfl_down(occ,  o, 64);
        surf += __shfl_down(surf, o, 64);
        over += __shfl_down(over, o, 64);
    }
    int lane = threadIdx.x & 63, wid = threadIdx.x >> 6;
    if (lane == 0) { sm[0][wid]=occ; sm[1][wid]=surf; sm[2][wid]=over; }
    __syncthreads();
    if (threadIdx.x == 0) {
        double so=0, ss=0, sv=0;
        for (int w = 0; w < 16; ++w) { so+=sm[0][w]; ss+=sm[1][w]; sv+=sm[2][w]; }
        double dS = (double)p_trap[0] + p_trap[1] + p_trap[2] + p_trap[3];
        double a_lo = 1.0 / (1.0 + exp(10.0));
        double N = (double)NTOT;
        double trap_sum = a_lo * (N - so) + dS;
        double occupancy = so / N;
        double occ_pen = 10.0 * (occupancy - 0.5) * (occupancy - 0.5);
        out[0] = (float)(sv / N);
        out[1] = (float)(ss / 27.0 / N - 100.0 * trap_sum / N - occ_pen);
    }
}

extern "C" void kernel_launch(void* const* d_in, const int* in_sizes, int n_in,
                              void* d_out, int out_size, void* d_ws, size_t ws_size,
                              hipStream_t stream)
{
    const float* v = (const float*)d_in[0];
    float* out = (float*)d_out;
    float* ws = (float*)d_ws;

    float* p_occ  = ws;
    float* p_surf = p_occ  + NBLK;
    float* p_over = p_surf + NBLK;
    float* p_trap = p_over + NBLK;   // 4 floats

    trap_box_k<<<4, dim3(4,16,16), 0, stream>>>(v, p_trap);
    reduce_all_k<<<dim3(16,128,4), dim3(32,8,1), 0, stream>>>(v, p_occ, p_surf, p_over);
    finalize_k<<<1, 1024, 0, stream>>>(p_occ, p_surf, p_over, p_trap, out);
}